// Round 12
// baseline (647.568 us; speedup 1.0000x reference)
//
#include <hip/hip_runtime.h>
#include <hip/hip_bf16.h>
#include <cstddef>

#define B_ 8
#define H_ 256
#define W_ 256

static constexpr int NPIX = B_ * H_ * W_;   // 524288

typedef __attribute__((ext_vector_type(8))) short bf16x8;   // 8 bf16 (4 VGPRs)
typedef __attribute__((ext_vector_type(4))) float f32x4;

__device__ __forceinline__ float4 ld4(const float* p) { return *(const float4*)p; }

// RNE f32 -> bf16 bits (finite data only)
__device__ __forceinline__ short f2bf(float x) {
    unsigned u = __float_as_uint(x);
    unsigned r = (u + 0x7fffu + ((u >> 16) & 1u)) >> 16;
    return (short)r;
}

// ---------------------------------------------------------------------------
// Convert f32 NHWC inputs -> bf16 copies (xb1, xb2). 8 floats/thread.
// ---------------------------------------------------------------------------
__global__ __launch_bounds__(256) void cvt_inputs_kernel(
    const float* __restrict__ in1, const float* __restrict__ in2,
    short* __restrict__ xb1, short* __restrict__ xb2)
{
    int t = blockIdx.x * 256 + threadIdx.x;          // 2 * NPIX*32/8 threads
    const int N8 = NPIX * 32 / 8;
    const float* src = (t < N8) ? in1 : in2;
    short* dst = (t < N8) ? xb1 : xb2;
    int i = (t < N8) ? t : t - N8;
    float4 a = ld4(src + (size_t)i * 8);
    float4 b = ld4(src + (size_t)i * 8 + 4);
    bf16x8 r;
    r[0] = f2bf(a.x); r[1] = f2bf(a.y); r[2] = f2bf(a.z); r[3] = f2bf(a.w);
    r[4] = f2bf(b.x); r[5] = f2bf(b.y); r[6] = f2bf(b.z); r[7] = f2bf(b.w);
    *(bf16x8*)(dst + (size_t)i * 8) = r;
}

// ---------------------------------------------------------------------------
// Pack conv weights into MFMA B-fragment order (bf16).
// Fragment lane layout (16x16x32): col = lane&15, k = 8*(lane>>4)+j.
// Per direction, 5248 lane-fragments:
//   [0,2304)    wb0: idx = ((t*2+c)*2+n)*64+l   (3x3, ci=64, co=32)
//   [2304,4608) wb1: idx = (t*4+n)*64+l         (3x3, ci=32, co=64)
//   [4608,5120) wb2: idx = (c*4+n)*64+l         (1x1, ci=64, co=64)
//   [5120,5248) wb3: idx = c*64+l               (1x1, ci=64, co=16)
// ---------------------------------------------------------------------------
__global__ __launch_bounds__(256) void prep_weights_kernel(
    const float* __restrict__ w0a, const float* __restrict__ w1a,
    const float* __restrict__ w2a, const float* __restrict__ w3a,
    const float* __restrict__ w0b, const float* __restrict__ w1b,
    const float* __restrict__ w2b, const float* __restrict__ w3b,
    short* __restrict__ wt0, short* __restrict__ wt1)
{
    int t = blockIdx.x * 256 + threadIdx.x;
    if (t >= 2 * 5248) return;
    int dir = t / 5248;
    int r = t % 5248;
    const float* w0 = dir ? w0b : w0a;
    const float* w1 = dir ? w1b : w1a;
    const float* w2 = dir ? w2b : w2a;
    const float* w3 = dir ? w3b : w3a;
    short* wt = dir ? wt1 : wt0;
    bf16x8 v;
    if (r < 2304) {
        int l = r & 63, n = (r >> 6) & 1, c = (r >> 7) & 1, tp = r >> 8;
#pragma unroll
        for (int j = 0; j < 8; ++j) {
            int ci = c * 32 + 8 * (l >> 4) + j;
            int co = n * 16 + (l & 15);
            v[j] = f2bf(w0[(size_t)(tp * 64 + ci) * 32 + co]);
        }
    } else if (r < 4608) {
        int q = r - 2304;
        int l = q & 63, n = (q >> 6) & 3, tp = q >> 8;
#pragma unroll
        for (int j = 0; j < 8; ++j) {
            int ci = 8 * (l >> 4) + j;
            int co = n * 16 + (l & 15);
            v[j] = f2bf(w1[(size_t)(tp * 32 + ci) * 64 + co]);
        }
    } else if (r < 5120) {
        int q = r - 4608;
        int l = q & 63, n = (q >> 6) & 3, c = q >> 8;
#pragma unroll
        for (int j = 0; j < 8; ++j) {
            int k = 32 * c + 8 * (l >> 4) + j;
            int co = n * 16 + (l & 15);
            v[j] = f2bf(w2[(size_t)k * 64 + co]);
        }
    } else {
        int q = r - 5120;
        int l = q & 63, c = q >> 6;
#pragma unroll
        for (int j = 0; j < 8; ++j) {
            int k = 32 * c + 8 * (l >> 4) + j;
            v[j] = f2bf(w3[(size_t)k * 16 + (l & 15)]);
        }
    }
    *(bf16x8*)(wt + (size_t)r * 8) = v;
}

// ---------------------------------------------------------------------------
// dense_image_warp (TFA semantics) -> bf16, both dirs. 4 threads/px, 8 ch.
// ---------------------------------------------------------------------------
__global__ __launch_bounds__(256) void warp_bf16_kernel(
    const float* __restrict__ in1, const float* __restrict__ in2,
    const float* __restrict__ fl12, const float* __restrict__ fl21,
    short* __restrict__ wbf)
{
    int gid = blockIdx.x * 256 + threadIdx.x;        // 2 * NPIX * 4
    int d   = (gid >= NPIX * 4);
    int g2  = gid - (d ? NPIX * 4 : 0);
    const float* img  = d ? in2 : in1;
    const float* flow = d ? fl21 : fl12;
    short* out = wbf + (size_t)d * NPIX * 32;

    int p   = g2 >> 2;
    int c8  = (g2 & 3) << 3;
    int b   = p >> 16;
    int i   = (p >> 8) & 255;
    int j   = p & 255;
    float2 f = *(const float2*)(flow + (size_t)p * 2);
    float qy = (float)i - f.x;
    float qx = (float)j - f.y;
    float fyf = fminf(fmaxf(floorf(qy), 0.0f), (float)(H_ - 2));
    float fxf = fminf(fmaxf(floorf(qx), 0.0f), (float)(W_ - 2));
    float ay = fminf(fmaxf(qy - fyf, 0.0f), 1.0f);
    float ax = fminf(fmaxf(qx - fxf, 0.0f), 1.0f);
    int fy = (int)fyf, fx = (int)fxf;
    const float* base = img + ((((size_t)b * H_ + fy) * W_ + fx) << 5) + c8;
    float4 tl0 = ld4(base),            tl1 = ld4(base + 4);
    float4 tr0 = ld4(base + 32),       tr1 = ld4(base + 36);
    float4 bl0 = ld4(base + W_ * 32),      bl1 = ld4(base + W_ * 32 + 4);
    float4 br0 = ld4(base + W_ * 32 + 32), br1 = ld4(base + W_ * 32 + 36);
    bf16x8 r;
#define WRP(k, TL, TR, BL, BR, m) \
    { float t = TL.m + ax * (TR.m - TL.m); float u = BL.m + ax * (BR.m - BL.m); r[k] = f2bf(t + ay * (u - t)); }
    WRP(0, tl0, tr0, bl0, br0, x) WRP(1, tl0, tr0, bl0, br0, y)
    WRP(2, tl0, tr0, bl0, br0, z) WRP(3, tl0, tr0, bl0, br0, w)
    WRP(4, tl1, tr1, bl1, br1, x) WRP(5, tl1, tr1, bl1, br1, y)
    WRP(6, tl1, tr1, bl1, br1, z) WRP(7, tl1, tr1, bl1, br1, w)
#undef WRP
    *(bf16x8*)(out + ((size_t)p << 5) + c8) = r;
}

// Final warp: f32 out to d_out, both dirs. 4 threads/px, 8 ch.
__global__ __launch_bounds__(256) void warp_f32_kernel(
    const float* __restrict__ in1, const float* __restrict__ in2,
    const float* __restrict__ fcb, float* __restrict__ outf)
{
    int gid = blockIdx.x * 256 + threadIdx.x;        // 2 * NPIX * 4
    int d   = (gid >= NPIX * 4);
    int g2  = gid - (d ? NPIX * 4 : 0);
    const float* img  = d ? in2 : in1;
    const float* flow = fcb + (size_t)d * NPIX * 2;
    float* out = outf + (size_t)d * NPIX * 32;

    int p   = g2 >> 2;
    int c8  = (g2 & 3) << 3;
    int b   = p >> 16;
    int i   = (p >> 8) & 255;
    int j   = p & 255;
    float2 f = *(const float2*)(flow + (size_t)p * 2);
    float qy = (float)i - f.x;
    float qx = (float)j - f.y;
    float fyf = fminf(fmaxf(floorf(qy), 0.0f), (float)(H_ - 2));
    float fxf = fminf(fmaxf(floorf(qx), 0.0f), (float)(W_ - 2));
    float ay = fminf(fmaxf(qy - fyf, 0.0f), 1.0f);
    float ax = fminf(fmaxf(qx - fxf, 0.0f), 1.0f);
    int fy = (int)fyf, fx = (int)fxf;
    const float* base = img + ((((size_t)b * H_ + fy) * W_ + fx) << 5) + c8;
    float4 tl0 = ld4(base),            tl1 = ld4(base + 4);
    float4 tr0 = ld4(base + 32),       tr1 = ld4(base + 36);
    float4 bl0 = ld4(base + W_ * 32),      bl1 = ld4(base + W_ * 32 + 4);
    float4 br0 = ld4(base + W_ * 32 + 32), br1 = ld4(base + W_ * 32 + 36);
    float4 r0, r1;
#define WRPF(D, k, TL, TR, BL, BR, m) \
    { float t = TL.m + ax * (TR.m - TL.m); float u = BL.m + ax * (BR.m - BL.m); D.k = t + ay * (u - t); }
    WRPF(r0, x, tl0, tr0, bl0, br0, x) WRPF(r0, y, tl0, tr0, bl0, br0, y)
    WRPF(r0, z, tl0, tr0, bl0, br0, z) WRPF(r0, w, tl0, tr0, bl0, br0, w)
    WRPF(r1, x, tl1, tr1, bl1, br1, x) WRPF(r1, y, tl1, tr1, bl1, br1, y)
    WRPF(r1, z, tl1, tr1, bl1, br1, z) WRPF(r1, w, tl1, tr1, bl1, br1, w)
#undef WRPF
    float* o = out + ((size_t)p << 5) + c8;
    *(float4*)o = r0;
    *(float4*)(o + 4) = r1;
}

// ---------------------------------------------------------------------------
// XCD-chunked swizzle for the 4096-block conv grids (4096 % 8 == 0, bijective):
// chunk c = orig&7 stays on one XCD and covers 512 consecutive logical blocks.
__device__ __forceinline__ int xcd_swz(int orig) {
    return (orig & 7) * 512 + (orig >> 3);
}

// ---------------------------------------------------------------------------
// conv0 MFMA, both dirs, 2 M-tiles/wave: 3x3, Cin=64 (A=other img, B=warped),
// Cout=32, ReLU -> bf16 h0. Block = 512 thr = 8 waves = 256 px = one row.
// ---------------------------------------------------------------------------
__global__ __launch_bounds__(512) void conv0_mfma_kernel(
    const short* __restrict__ xb1, const short* __restrict__ xb2,
    const short* __restrict__ wbf,
    const short* __restrict__ wt0, const short* __restrict__ wt1,
    const float* __restrict__ b0a, const float* __restrict__ b0b,
    short* __restrict__ h0)
{
    __shared__ short swt[2304 * 8];          // 36 KB
    int wg  = xcd_swz(blockIdx.x);
    int d   = wg >> 11;                      // 2048 blocks per dir
    int bid = wg & 2047;
    const short* xoth = d ? xb1 : xb2;
    const short* xw   = wbf + (size_t)d * NPIX * 32;
    const short* wtab = d ? wt1 : wt0;
    const float* bias = d ? b0b : b0a;
    short* out = h0 + (size_t)d * NPIX * 32;

    int tid = threadIdx.x;
    for (int i = tid; i < 2304; i += 512)
        ((bf16x8*)swt)[i] = ((const bf16x8*)wtab)[i];
    __syncthreads();

    int wave = tid >> 6, lane = tid & 63;
    int l15 = lane & 15, g = lane >> 4;
    int prow = bid * 256;                    // row start pixel
    int y    = bid & 255;
    int t0   = prow + wave * 32;             // tile0 base px
    int xl0  = wave * 32 + l15;              // column of tile0 lane px
    int xl1  = xl0 + 16;

    const short* a0p = xoth + ((size_t)(t0 + l15) << 5) + g * 8;
    const short* a1p = a0p + (16 << 5);
    const short* b0p = xw + ((size_t)(t0 + l15) << 5) + g * 8;
    const short* b1p = b0p + (16 << 5);
    const bf16x8* wfrag = (const bf16x8*)swt;

    float bv0 = bias[l15], bv1 = bias[16 + l15];
    f32x4 acc00 = {bv0, bv0, bv0, bv0};      // tile0, co 0-15
    f32x4 acc01 = {bv1, bv1, bv1, bv1};      // tile0, co 16-31
    f32x4 acc10 = {bv0, bv0, bv0, bv0};      // tile1, co 0-15
    f32x4 acc11 = {bv1, bv1, bv1, bv1};
    const bf16x8 z8 = {0, 0, 0, 0, 0, 0, 0, 0};

#pragma unroll
    for (int dy = -1; dy <= 1; ++dy) {
        if ((unsigned)(y + dy) >= (unsigned)H_) continue;   // uniform per block
#pragma unroll
        for (int dx = -1; dx <= 1; ++dx) {
            bool v0 = (unsigned)(xl0 + dx) < (unsigned)W_;
            bool v1 = (unsigned)(xl1 + dx) < (unsigned)W_;
            int off0 = (dy * W_ + (v0 ? dx : 0)) << 5;
            int off1 = (dy * W_ + (v1 ? dx : 0)) << 5;
            bf16x8 aA0 = *(const bf16x8*)(a0p + off0);
            bf16x8 aB0 = *(const bf16x8*)(b0p + off0);
            bf16x8 aA1 = *(const bf16x8*)(a1p + off1);
            bf16x8 aB1 = *(const bf16x8*)(b1p + off1);
            aA0 = v0 ? aA0 : z8;  aB0 = v0 ? aB0 : z8;
            aA1 = v1 ? aA1 : z8;  aB1 = v1 ? aB1 : z8;
            int t = (dy + 1) * 3 + (dx + 1);
            bf16x8 w0 = wfrag[(t * 4 + 0) * 64 + lane];
            bf16x8 w1 = wfrag[(t * 4 + 1) * 64 + lane];
            bf16x8 w2 = wfrag[(t * 4 + 2) * 64 + lane];
            bf16x8 w3 = wfrag[(t * 4 + 3) * 64 + lane];
            acc00 = __builtin_amdgcn_mfma_f32_16x16x32_bf16(aA0, w0, acc00, 0, 0, 0);
            acc01 = __builtin_amdgcn_mfma_f32_16x16x32_bf16(aA0, w1, acc01, 0, 0, 0);
            acc10 = __builtin_amdgcn_mfma_f32_16x16x32_bf16(aA1, w0, acc10, 0, 0, 0);
            acc11 = __builtin_amdgcn_mfma_f32_16x16x32_bf16(aA1, w1, acc11, 0, 0, 0);
            acc00 = __builtin_amdgcn_mfma_f32_16x16x32_bf16(aB0, w2, acc00, 0, 0, 0);
            acc01 = __builtin_amdgcn_mfma_f32_16x16x32_bf16(aB0, w3, acc01, 0, 0, 0);
            acc10 = __builtin_amdgcn_mfma_f32_16x16x32_bf16(aB1, w2, acc10, 0, 0, 0);
            acc11 = __builtin_amdgcn_mfma_f32_16x16x32_bf16(aB1, w3, acc11, 0, 0, 0);
        }
    }

    // C/D: col(co)=l15, row(px)=g*4+r
#pragma unroll
    for (int r = 0; r < 4; ++r) {
        size_t r0 = (size_t)(t0 + g * 4 + r) << 5;
        size_t r1 = (size_t)(t0 + 16 + g * 4 + r) << 5;
        out[r0 + l15]      = f2bf(fmaxf(acc00[r], 0.f));
        out[r0 + 16 + l15] = f2bf(fmaxf(acc01[r], 0.f));
        out[r1 + l15]      = f2bf(fmaxf(acc10[r], 0.f));
        out[r1 + 16 + l15] = f2bf(fmaxf(acc11[r], 0.f));
    }
}

// ---------------------------------------------------------------------------
// conv1 MFMA fused, both dirs, 2 M-tiles/wave.
// LDS: W1 only (36 KB) + per-wave [16][64] tile (16 KB) = 52 KB -> 3 blk/CU.
// W2/W3 (10 KB, L2-hot) loaded to registers after GEMM1. Tiles run GEMM2/3
// sequentially, reusing the wave-private swizzled tile buffer.
// ---------------------------------------------------------------------------
__global__ __launch_bounds__(512) void conv1_mfma_kernel(
    const short* __restrict__ h0,
    const short* __restrict__ wt0, const short* __restrict__ wt1,
    const float* __restrict__ b1a, const float* __restrict__ b1b,
    const float* __restrict__ b2a, const float* __restrict__ b2b,
    const float* __restrict__ b3a, const float* __restrict__ b3b,
    const float* __restrict__ w4a, const float* __restrict__ w4b,
    const float* __restrict__ b4a, const float* __restrict__ b4b,
    const float* __restrict__ fl12, const float* __restrict__ fl21,
    float* __restrict__ fcb)
{
    __shared__ short swt[2304 * 8];                 // W1 only: 36 KB
    __shared__ __align__(16) short sx[8][1024];     // 8 waves x [16][64] = 16 KB
    int wg  = xcd_swz(blockIdx.x);
    int d   = wg >> 11;
    int bid = wg & 2047;
    const short* hsrc = h0 + (size_t)d * NPIX * 32;
    const short* wtab = (d ? wt1 : wt0) + 2304 * 8;   // chain table (frag base)
    const float* b1 = d ? b1b : b1a;
    const float* b2 = d ? b2b : b2a;
    const float* b3 = d ? b3b : b3a;
    const float* w4 = d ? w4b : w4a;
    const float* b4 = d ? b4b : b4a;
    const float* flow = d ? fl21 : fl12;
    float* fc = fcb + (size_t)d * NPIX * 2;

    int tid = threadIdx.x;
    for (int i = tid; i < 2304; i += 512)
        ((bf16x8*)swt)[i] = ((const bf16x8*)wtab)[i];
    __syncthreads();

    int wave = tid >> 6, lane = tid & 63;
    int l15 = lane & 15, g = lane >> 4;
    int prow = bid * 256;
    int y    = bid & 255;
    int t0   = prow + wave * 32;
    int xl0  = wave * 32 + l15;
    int xl1  = xl0 + 16;

    const short* a0p = hsrc + ((size_t)(t0 + l15) << 5) + g * 8;
    const short* a1p = a0p + (16 << 5);
    const bf16x8* W1 = (const bf16x8*)swt;            // LDS: (t*4+n)*64+lane
    const bf16x8* W2g = (const bf16x8*)wtab + 2304;   // global: (c*4+n)*64+lane
    const bf16x8* W3g = (const bf16x8*)wtab + 2816;   // global: c*64+lane
    char* xb = (char*)&sx[wave][0];
    const bf16x8 z8 = {0, 0, 0, 0, 0, 0, 0, 0};

    // ---- GEMM1: 3x3, 32 -> 64, both tiles ----
    f32x4 acc0[4], acc1[4];
#pragma unroll
    for (int n = 0; n < 4; ++n) {
        float b = b1[n * 16 + l15];
        acc0[n] = (f32x4){b, b, b, b};
        acc1[n] = (f32x4){b, b, b, b};
    }
#pragma unroll
    for (int dy = -1; dy <= 1; ++dy) {
        if ((unsigned)(y + dy) >= (unsigned)H_) continue;
#pragma unroll
        for (int dx = -1; dx <= 1; ++dx) {
            bool v0 = (unsigned)(xl0 + dx) < (unsigned)W_;
            bool v1 = (unsigned)(xl1 + dx) < (unsigned)W_;
            int off0 = (dy * W_ + (v0 ? dx : 0)) << 5;
            int off1 = (dy * W_ + (v1 ? dx : 0)) << 5;
            bf16x8 a0 = *(const bf16x8*)(a0p + off0);
            bf16x8 a1 = *(const bf16x8*)(a1p + off1);
            a0 = v0 ? a0 : z8;
            a1 = v1 ? a1 : z8;
            int t = (dy + 1) * 3 + (dx + 1);
#pragma unroll
            for (int n = 0; n < 4; ++n) {
                bf16x8 w = W1[(t * 4 + n) * 64 + lane];
                acc0[n] = __builtin_amdgcn_mfma_f32_16x16x32_bf16(a0, w, acc0[n], 0, 0, 0);
                acc1[n] = __builtin_amdgcn_mfma_f32_16x16x32_bf16(a1, w, acc1[n], 0, 0, 0);
            }
        }
    }

    // Hoist W2/W3 fragments into registers (L2-hot, reused for both tiles)
    bf16x8 w2r[8], w3r[2];
#pragma unroll
    for (int c = 0; c < 2; ++c) {
#pragma unroll
        for (int n = 0; n < 4; ++n)
            w2r[c * 4 + n] = W2g[(c * 4 + n) * 64 + lane];
        w3r[c] = W3g[c * 64 + lane];
    }

    float b3v = b3[l15];
    float w40 = w4[l15 * 2 + 0], w41 = w4[l15 * 2 + 1];
    float bb0 = b4[0], bb1 = b4[1];
    float b2v[4];
#pragma unroll
    for (int n = 0; n < 4; ++n) b2v[n] = b2[n * 16 + l15];

    // ---- per-tile tail: GEMM2 (1x1 64->64), GEMM3 (1x1 64->16), 16->2 ----
    auto tail = [&](f32x4 (&accT)[4], int tbase) {
        // relu -> bf16 -> swizzled LDS [16 px][64 ch]
#pragma unroll
        for (int n = 0; n < 4; ++n)
#pragma unroll
            for (int r = 0; r < 4; ++r) {
                int row = g * 4 + r, ch = n * 16 + l15;
                int by = (row * 128 + ch * 2) ^ ((row & 7) << 4);
                *(short*)(xb + by) = f2bf(fmaxf(accT[n][r], 0.f));
            }
        f32x4 t2[4];
#pragma unroll
        for (int n = 0; n < 4; ++n) t2[n] = (f32x4){b2v[n], b2v[n], b2v[n], b2v[n]};
#pragma unroll
        for (int c = 0; c < 2; ++c) {
            int by = (l15 * 128 + (32 * c + 8 * g) * 2) ^ ((l15 & 7) << 4);
            bf16x8 a = *(const bf16x8*)(xb + by);
#pragma unroll
            for (int n = 0; n < 4; ++n)
                t2[n] = __builtin_amdgcn_mfma_f32_16x16x32_bf16(a, w2r[c * 4 + n], t2[n], 0, 0, 0);
        }
#pragma unroll
        for (int n = 0; n < 4; ++n)
#pragma unroll
            for (int r = 0; r < 4; ++r) {
                int row = g * 4 + r, ch = n * 16 + l15;
                int by = (row * 128 + ch * 2) ^ ((row & 7) << 4);
                *(short*)(xb + by) = f2bf(fmaxf(t2[n][r], 0.f));
            }
        f32x4 a3 = {b3v, b3v, b3v, b3v};
#pragma unroll
        for (int c = 0; c < 2; ++c) {
            int by = (l15 * 128 + (32 * c + 8 * g) * 2) ^ ((l15 & 7) << 4);
            bf16x8 a = *(const bf16x8*)(xb + by);
            a3 = __builtin_amdgcn_mfma_f32_16x16x32_bf16(a, w3r[c], a3, 0, 0, 0);
        }
#pragma unroll
        for (int r = 0; r < 4; ++r) {
            float v = fmaxf(a3[r], 0.f);
            float s0 = v * w40, s1 = v * w41;
#pragma unroll
            for (int m = 1; m < 16; m <<= 1) {
                s0 += __shfl_xor(s0, m);
                s1 += __shfl_xor(s1, m);
            }
            if (l15 == 0) {
                int pr = tbase + g * 4 + r;
                float2 fl = *(const float2*)(flow + (size_t)pr * 2);
                float2 o; o.x = fl.x + bb0 + s0; o.y = fl.y + bb1 + s1;
                *(float2*)(fc + (size_t)pr * 2) = o;
            }
        }
    };
    tail(acc0, t0);
    tail(acc1, t0 + 16);
}

// ---------------------------------------------------------------------------
// 2x bilinear upsample (jax half-pixel), both dirs.
// ---------------------------------------------------------------------------
__global__ __launch_bounds__(256) void upsample_kernel(
    const float* __restrict__ fcb, float* __restrict__ outup)
{
    int gid = blockIdx.x * 256 + threadIdx.x;       // 2 * B*512*512
    const int NUP = B_ * 512 * 512;
    int d  = (gid >= NUP);
    int g2 = gid - (d ? NUP : 0);
    const float* fc = fcb + (size_t)d * NPIX * 2;
    float* out = outup + (size_t)d * NUP * 2;

    int b  = g2 >> 18;
    int oy = (g2 >> 9) & 511;
    int ox = g2 & 511;
    float iy = 0.5f * (float)oy - 0.25f;
    float ix = 0.5f * (float)ox - 0.25f;
    float y0f = floorf(iy), x0f = floorf(ix);
    float wy = iy - y0f, wx = ix - x0f;
    int y0 = min(max((int)y0f, 0), H_ - 1);
    int y1 = min(max((int)y0f + 1, 0), H_ - 1);
    int x0 = min(max((int)x0f, 0), W_ - 1);
    int x1 = min(max((int)x0f + 1, 0), W_ - 1);
    float2 v00 = *(const float2*)(fc + (((size_t)b * H_ + y0) * W_ + x0) * 2);
    float2 v01 = *(const float2*)(fc + (((size_t)b * H_ + y0) * W_ + x1) * 2);
    float2 v10 = *(const float2*)(fc + (((size_t)b * H_ + y1) * W_ + x0) * 2);
    float2 v11 = *(const float2*)(fc + (((size_t)b * H_ + y1) * W_ + x1) * 2);
    float2 r;
    { float t = v00.x + wx * (v01.x - v00.x); float u = v10.x + wx * (v11.x - v10.x); r.x = t + wy * (u - t); }
    { float t = v00.y + wx * (v01.y - v00.y); float u = v10.y + wx * (v11.y - v10.y); r.y = t + wy * (u - t); }
    *(float2*)(out + (size_t)g2 * 2) = r;
}

// ---------------------------------------------------------------------------
// d_in order = setup_inputs() dict order (interleaved per layer):
//   w_i = d_in[4+4i+2d], b_i = d_in[5+4i+2d]
// ---------------------------------------------------------------------------
extern "C" void kernel_launch(void* const* d_in, const int* in_sizes, int n_in,
                              void* d_out, int out_size, void* d_ws, size_t ws_size,
                              hipStream_t stream)
{
    (void)in_sizes; (void)n_in; (void)out_size; (void)ws_size;
    const float* input1 = (const float*)d_in[0];
    const float* input2 = (const float*)d_in[1];
    const float* fl12 = (const float*)d_in[2];
    const float* fl21 = (const float*)d_in[3];
    char* wsb = (char*)d_ws;
    short* xb1  = (short*)(wsb);                       // 32MB
    short* xb2  = (short*)(wsb + 33554432);            // 32MB
    short* wbf  = (short*)(wsb + 67108864);            // 2 x 32MB
    short* h0   = (short*)(wsb + 134217728);           // 2 x 32MB
    float* fcb  = (float*)(wsb + 201326592);           // 2 x 4MB
    short* wt0  = (short*)(wsb + 209715200);           // 5248*16 B
    short* wt1  = (short*)(wsb + 209715200 + 5248 * 16);
    float* outf = (float*)d_out;
    float* outup = outf + (size_t)2 * NPIX * 32;

    cvt_inputs_kernel<<<NPIX * 64 / 8 / 256, 256, 0, stream>>>(input1, input2, xb1, xb2);
    prep_weights_kernel<<<(2 * 5248 + 255) / 256, 256, 0, stream>>>(
        (const float*)d_in[4],  (const float*)d_in[8],  (const float*)d_in[12], (const float*)d_in[16],
        (const float*)d_in[6],  (const float*)d_in[10], (const float*)d_in[14], (const float*)d_in[18],
        wt0, wt1);
    warp_bf16_kernel<<<2 * NPIX * 4 / 256, 256, 0, stream>>>(input1, input2, fl12, fl21, wbf);
    conv0_mfma_kernel<<<2 * NPIX / 256, 512, 0, stream>>>(
        xb1, xb2, wbf, wt0, wt1,
        (const float*)d_in[5], (const float*)d_in[7], h0);
    conv1_mfma_kernel<<<2 * NPIX / 256, 512, 0, stream>>>(
        h0, wt0, wt1,
        (const float*)d_in[9],  (const float*)d_in[11],
        (const float*)d_in[13], (const float*)d_in[15],
        (const float*)d_in[17], (const float*)d_in[19],
        (const float*)d_in[20], (const float*)d_in[22],
        (const float*)d_in[21], (const float*)d_in[23],
        fl12, fl21, fcb);
    warp_f32_kernel<<<2 * NPIX * 4 / 256, 256, 0, stream>>>(input1, input2, fcb, outf);
    upsample_kernel<<<2 * B_ * 512 * 512 / 256, 256, 0, stream>>>(fcb, outup);
}

// Round 13
// 581.146 us; speedup vs baseline: 1.1143x; 1.1143x over previous
//
#include <hip/hip_runtime.h>
#include <hip/hip_bf16.h>
#include <cstddef>

#define B_ 8
#define H_ 256
#define W_ 256

static constexpr int NPIX = B_ * H_ * W_;   // 524288

typedef __attribute__((ext_vector_type(8))) short bf16x8;   // 8 bf16 (4 VGPRs)
typedef __attribute__((ext_vector_type(4))) float f32x4;

__device__ __forceinline__ float4 ld4(const float* p) { return *(const float4*)p; }

// RNE f32 -> bf16 bits (finite data only)
__device__ __forceinline__ short f2bf(float x) {
    unsigned u = __float_as_uint(x);
    unsigned r = (u + 0x7fffu + ((u >> 16) & 1u)) >> 16;
    return (short)r;
}

// ---------------------------------------------------------------------------
// Bodies for the grid-partitioned pre/post mega-kernels.
// ---------------------------------------------------------------------------
__device__ __forceinline__ void warp_bf16_body(
    int gid, const float* __restrict__ in1, const float* __restrict__ in2,
    const float* __restrict__ fl12, const float* __restrict__ fl21,
    short* __restrict__ wbf)
{
    int d   = (gid >= NPIX * 8);
    int g2  = gid - (d ? NPIX * 8 : 0);
    const float* img  = d ? in2 : in1;
    const float* flow = d ? fl21 : fl12;
    short* out = wbf + (size_t)d * NPIX * 32;

    int p   = g2 >> 3;
    int c4  = (g2 & 7) << 2;
    int b   = p >> 16;
    int i   = (p >> 8) & 255;
    int j   = p & 255;
    float2 f = *(const float2*)(flow + (size_t)p * 2);
    float qy = (float)i - f.x;
    float qx = (float)j - f.y;
    float fyf = fminf(fmaxf(floorf(qy), 0.0f), (float)(H_ - 2));
    float fxf = fminf(fmaxf(floorf(qx), 0.0f), (float)(W_ - 2));
    float ay = fminf(fmaxf(qy - fyf, 0.0f), 1.0f);
    float ax = fminf(fmaxf(qx - fxf, 0.0f), 1.0f);
    int fy = (int)fyf, fx = (int)fxf;
    const float* base = img + ((((size_t)b * H_ + fy) * W_ + fx) << 5) + c4;
    float4 tl = ld4(base);
    float4 tr = ld4(base + 32);
    float4 bl = ld4(base + W_ * 32);
    float4 br = ld4(base + W_ * 32 + 32);
    short4 r;
    { float t = tl.x + ax * (tr.x - tl.x); float u = bl.x + ax * (br.x - bl.x); r.x = f2bf(t + ay * (u - t)); }
    { float t = tl.y + ax * (tr.y - tl.y); float u = bl.y + ax * (br.y - bl.y); r.y = f2bf(t + ay * (u - t)); }
    { float t = tl.z + ax * (tr.z - tl.z); float u = bl.z + ax * (br.z - bl.z); r.z = f2bf(t + ay * (u - t)); }
    { float t = tl.w + ax * (tr.w - tl.w); float u = bl.w + ax * (br.w - bl.w); r.w = f2bf(t + ay * (u - t)); }
    *(short4*)(out + ((size_t)p << 5) + c4) = r;
}

__device__ __forceinline__ void cvt_body(
    int t, const float* __restrict__ in1, const float* __restrict__ in2,
    short* __restrict__ xb1, short* __restrict__ xb2)
{
    const int N8 = NPIX * 32 / 8;
    const float* src = (t < N8) ? in1 : in2;
    short* dst = (t < N8) ? xb1 : xb2;
    int i = (t < N8) ? t : t - N8;
    float4 a = ld4(src + (size_t)i * 8);
    float4 b = ld4(src + (size_t)i * 8 + 4);
    bf16x8 r;
    r[0] = f2bf(a.x); r[1] = f2bf(a.y); r[2] = f2bf(a.z); r[3] = f2bf(a.w);
    r[4] = f2bf(b.x); r[5] = f2bf(b.y); r[6] = f2bf(b.z); r[7] = f2bf(b.w);
    *(bf16x8*)(dst + (size_t)i * 8) = r;
}

// Pack conv weights into MFMA B-fragment order (bf16).
// Fragment lane layout (16x16x32): col = lane&15, k = 8*(lane>>4)+j.
__device__ __forceinline__ void prep_body(
    int t,
    const float* __restrict__ w0a, const float* __restrict__ w1a,
    const float* __restrict__ w2a, const float* __restrict__ w3a,
    const float* __restrict__ w0b, const float* __restrict__ w1b,
    const float* __restrict__ w2b, const float* __restrict__ w3b,
    short* __restrict__ wt0, short* __restrict__ wt1)
{
    if (t >= 2 * 5248) return;
    int dir = t / 5248;
    int r = t % 5248;
    const float* w0 = dir ? w0b : w0a;
    const float* w1 = dir ? w1b : w1a;
    const float* w2 = dir ? w2b : w2a;
    const float* w3 = dir ? w3b : w3a;
    short* wt = dir ? wt1 : wt0;
    bf16x8 v;
    if (r < 2304) {
        int l = r & 63, n = (r >> 6) & 1, c = (r >> 7) & 1, tp = r >> 8;
#pragma unroll
        for (int j = 0; j < 8; ++j) {
            int ci = c * 32 + 8 * (l >> 4) + j;
            int co = n * 16 + (l & 15);
            v[j] = f2bf(w0[(size_t)(tp * 64 + ci) * 32 + co]);
        }
    } else if (r < 4608) {
        int q = r - 2304;
        int l = q & 63, n = (q >> 6) & 3, tp = q >> 8;
#pragma unroll
        for (int j = 0; j < 8; ++j) {
            int ci = 8 * (l >> 4) + j;
            int co = n * 16 + (l & 15);
            v[j] = f2bf(w1[(size_t)(tp * 32 + ci) * 64 + co]);
        }
    } else if (r < 5120) {
        int q = r - 4608;
        int l = q & 63, n = (q >> 6) & 3, c = q >> 8;
#pragma unroll
        for (int j = 0; j < 8; ++j) {
            int k = 32 * c + 8 * (l >> 4) + j;
            int co = n * 16 + (l & 15);
            v[j] = f2bf(w2[(size_t)k * 64 + co]);
        }
    } else {
        int q = r - 5120;
        int l = q & 63, c = q >> 6;
#pragma unroll
        for (int j = 0; j < 8; ++j) {
            int k = 32 * c + 8 * (l >> 4) + j;
            v[j] = f2bf(w3[(size_t)k * 16 + (l & 15)]);
        }
    }
    *(bf16x8*)(wt + (size_t)r * 8) = v;
}

// ---------------------------------------------------------------------------
// PRE mega-kernel: [0,NW) warp_bf16, [NW,NW+NC) cvt, rest prep_weights.
// ---------------------------------------------------------------------------
__global__ __launch_bounds__(256) void pre_kernel(
    const float* __restrict__ in1, const float* __restrict__ in2,
    const float* __restrict__ fl12, const float* __restrict__ fl21,
    short* __restrict__ xb1, short* __restrict__ xb2, short* __restrict__ wbf,
    const float* __restrict__ w0a, const float* __restrict__ w1a,
    const float* __restrict__ w2a, const float* __restrict__ w3a,
    const float* __restrict__ w0b, const float* __restrict__ w1b,
    const float* __restrict__ w2b, const float* __restrict__ w3b,
    short* __restrict__ wt0, short* __restrict__ wt1)
{
    const int NW = 2 * NPIX * 8 / 256;    // 32768 warp blocks
    const int NC = NPIX * 64 / 8 / 256;   // 16384 cvt blocks
    int blk = blockIdx.x;
    if (blk < NW) {
        warp_bf16_body(blk * 256 + threadIdx.x, in1, in2, fl12, fl21, wbf);
    } else if (blk < NW + NC) {
        cvt_body((blk - NW) * 256 + threadIdx.x, in1, in2, xb1, xb2);
    } else {
        prep_body((blk - NW - NC) * 256 + threadIdx.x,
                  w0a, w1a, w2a, w3a, w0b, w1b, w2b, w3b, wt0, wt1);
    }
}

// ---------------------------------------------------------------------------
// XCD-chunked swizzle for the 4096-block conv grids (4096 % 8 == 0, bijective)
__device__ __forceinline__ int xcd_swz(int orig) {
    return (orig & 7) * 512 + (orig >> 3);
}

// ---------------------------------------------------------------------------
// conv0 MFMA, both dirs, 2 M-tiles/wave: 3x3, Cin=64 (A=other img, B=warped),
// Cout=32, ReLU -> bf16 h0. Block = 512 thr = 8 waves = 256 px = one row.
// ---------------------------------------------------------------------------
__global__ __launch_bounds__(512) void conv0_mfma_kernel(
    const short* __restrict__ xb1, const short* __restrict__ xb2,
    const short* __restrict__ wbf,
    const short* __restrict__ wt0, const short* __restrict__ wt1,
    const float* __restrict__ b0a, const float* __restrict__ b0b,
    short* __restrict__ h0)
{
    __shared__ short swt[2304 * 8];          // 36 KB
    int wg  = xcd_swz(blockIdx.x);
    int d   = wg >> 11;                      // 2048 blocks per dir
    int bid = wg & 2047;
    const short* xoth = d ? xb1 : xb2;
    const short* xw   = wbf + (size_t)d * NPIX * 32;
    const short* wtab = d ? wt1 : wt0;
    const float* bias = d ? b0b : b0a;
    short* out = h0 + (size_t)d * NPIX * 32;

    int tid = threadIdx.x;
    for (int i = tid; i < 2304; i += 512)
        ((bf16x8*)swt)[i] = ((const bf16x8*)wtab)[i];
    __syncthreads();

    int wave = tid >> 6, lane = tid & 63;
    int l15 = lane & 15, g = lane >> 4;
    int prow = bid * 256;                    // row start pixel
    int y    = bid & 255;
    int t0   = prow + wave * 32;             // tile0 base px
    int xl0  = wave * 32 + l15;              // column of tile0 lane px
    int xl1  = xl0 + 16;

    const short* a0p = xoth + ((size_t)(t0 + l15) << 5) + g * 8;
    const short* a1p = a0p + (16 << 5);
    const short* b0p = xw + ((size_t)(t0 + l15) << 5) + g * 8;
    const short* b1p = b0p + (16 << 5);
    const bf16x8* wfrag = (const bf16x8*)swt;

    float bv0 = bias[l15], bv1 = bias[16 + l15];
    f32x4 acc00 = {bv0, bv0, bv0, bv0};      // tile0, co 0-15
    f32x4 acc01 = {bv1, bv1, bv1, bv1};      // tile0, co 16-31
    f32x4 acc10 = {bv0, bv0, bv0, bv0};      // tile1, co 0-15
    f32x4 acc11 = {bv1, bv1, bv1, bv1};
    const bf16x8 z8 = {0, 0, 0, 0, 0, 0, 0, 0};

#pragma unroll
    for (int dy = -1; dy <= 1; ++dy) {
        if ((unsigned)(y + dy) >= (unsigned)H_) continue;   // uniform per block
#pragma unroll
        for (int dx = -1; dx <= 1; ++dx) {
            bool v0 = (unsigned)(xl0 + dx) < (unsigned)W_;
            bool v1 = (unsigned)(xl1 + dx) < (unsigned)W_;
            int off0 = (dy * W_ + (v0 ? dx : 0)) << 5;
            int off1 = (dy * W_ + (v1 ? dx : 0)) << 5;
            bf16x8 aA0 = *(const bf16x8*)(a0p + off0);
            bf16x8 aB0 = *(const bf16x8*)(b0p + off0);
            bf16x8 aA1 = *(const bf16x8*)(a1p + off1);
            bf16x8 aB1 = *(const bf16x8*)(b1p + off1);
            aA0 = v0 ? aA0 : z8;  aB0 = v0 ? aB0 : z8;
            aA1 = v1 ? aA1 : z8;  aB1 = v1 ? aB1 : z8;
            int t = (dy + 1) * 3 + (dx + 1);
            bf16x8 w0 = wfrag[(t * 4 + 0) * 64 + lane];
            bf16x8 w1 = wfrag[(t * 4 + 1) * 64 + lane];
            bf16x8 w2 = wfrag[(t * 4 + 2) * 64 + lane];
            bf16x8 w3 = wfrag[(t * 4 + 3) * 64 + lane];
            acc00 = __builtin_amdgcn_mfma_f32_16x16x32_bf16(aA0, w0, acc00, 0, 0, 0);
            acc01 = __builtin_amdgcn_mfma_f32_16x16x32_bf16(aA0, w1, acc01, 0, 0, 0);
            acc10 = __builtin_amdgcn_mfma_f32_16x16x32_bf16(aA1, w0, acc10, 0, 0, 0);
            acc11 = __builtin_amdgcn_mfma_f32_16x16x32_bf16(aA1, w1, acc11, 0, 0, 0);
            acc00 = __builtin_amdgcn_mfma_f32_16x16x32_bf16(aB0, w2, acc00, 0, 0, 0);
            acc01 = __builtin_amdgcn_mfma_f32_16x16x32_bf16(aB0, w3, acc01, 0, 0, 0);
            acc10 = __builtin_amdgcn_mfma_f32_16x16x32_bf16(aB1, w2, acc10, 0, 0, 0);
            acc11 = __builtin_amdgcn_mfma_f32_16x16x32_bf16(aB1, w3, acc11, 0, 0, 0);
        }
    }

    // C/D: col(co)=l15, row(px)=g*4+r
#pragma unroll
    for (int r = 0; r < 4; ++r) {
        size_t r0 = (size_t)(t0 + g * 4 + r) << 5;
        size_t r1 = (size_t)(t0 + 16 + g * 4 + r) << 5;
        out[r0 + l15]      = f2bf(fmaxf(acc00[r], 0.f));
        out[r0 + 16 + l15] = f2bf(fmaxf(acc01[r], 0.f));
        out[r1 + l15]      = f2bf(fmaxf(acc10[r], 0.f));
        out[r1 + 16 + l15] = f2bf(fmaxf(acc11[r], 0.f));
    }
}

// ---------------------------------------------------------------------------
// conv1 MFMA fused (R11 structure + XCD swizzle), both dirs, 2 M-tiles/wave:
// 3x3 32->64 relu, 1x1 64->64 relu, 1x1 64->16 relu, 1x1 16->2 (+flow).
// W1|W2|W3 in 46 KB LDS; wave-private swizzled tile [32 px][64 ch] (32 KB).
// ---------------------------------------------------------------------------
__global__ __launch_bounds__(512) void conv1_mfma_kernel(
    const short* __restrict__ h0,
    const short* __restrict__ wt0, const short* __restrict__ wt1,
    const float* __restrict__ b1a, const float* __restrict__ b1b,
    const float* __restrict__ b2a, const float* __restrict__ b2b,
    const float* __restrict__ b3a, const float* __restrict__ b3b,
    const float* __restrict__ w4a, const float* __restrict__ w4b,
    const float* __restrict__ b4a, const float* __restrict__ b4b,
    const float* __restrict__ fl12, const float* __restrict__ fl21,
    float* __restrict__ fcb)
{
    __shared__ short swt[2944 * 8];                 // wb1|wb2|wb3 = 46 KB
    __shared__ __align__(16) short sx[8][2048];     // 8 waves x [32][64] = 32 KB
    int wg  = xcd_swz(blockIdx.x);
    int d   = wg >> 11;
    int bid = wg & 2047;
    const short* hsrc = h0 + (size_t)d * NPIX * 32;
    const short* wtab = (d ? wt1 : wt0) + 2304 * 8;
    const float* b1 = d ? b1b : b1a;
    const float* b2 = d ? b2b : b2a;
    const float* b3 = d ? b3b : b3a;
    const float* w4 = d ? w4b : w4a;
    const float* b4 = d ? b4b : b4a;
    const float* flow = d ? fl21 : fl12;
    float* fc = fcb + (size_t)d * NPIX * 2;

    int tid = threadIdx.x;
    for (int i = tid; i < 2944; i += 512)
        ((bf16x8*)swt)[i] = ((const bf16x8*)wtab)[i];
    __syncthreads();

    int wave = tid >> 6, lane = tid & 63;
    int l15 = lane & 15, g = lane >> 4;
    int prow = bid * 256;
    int y    = bid & 255;
    int t0   = prow + wave * 32;
    int xl0  = wave * 32 + l15;
    int xl1  = xl0 + 16;

    const short* a0p = hsrc + ((size_t)(t0 + l15) << 5) + g * 8;
    const short* a1p = a0p + (16 << 5);
    const bf16x8* W1 = (const bf16x8*)swt;          // (t*4+n)*64+lane
    const bf16x8* W2 = (const bf16x8*)swt + 2304;   // (c*4+n)*64+lane
    const bf16x8* W3 = (const bf16x8*)swt + 2816;   // c*64+lane
    char* xb = (char*)&sx[wave][0];
    const bf16x8 z8 = {0, 0, 0, 0, 0, 0, 0, 0};

    // ---- GEMM1: 3x3, 32 -> 64 ----
    f32x4 acc0[4], acc1[4];
#pragma unroll
    for (int n = 0; n < 4; ++n) {
        float b = b1[n * 16 + l15];
        acc0[n] = (f32x4){b, b, b, b};
        acc1[n] = (f32x4){b, b, b, b};
    }
#pragma unroll
    for (int dy = -1; dy <= 1; ++dy) {
        if ((unsigned)(y + dy) >= (unsigned)H_) continue;
#pragma unroll
        for (int dx = -1; dx <= 1; ++dx) {
            bool v0 = (unsigned)(xl0 + dx) < (unsigned)W_;
            bool v1 = (unsigned)(xl1 + dx) < (unsigned)W_;
            int off0 = (dy * W_ + (v0 ? dx : 0)) << 5;
            int off1 = (dy * W_ + (v1 ? dx : 0)) << 5;
            bf16x8 a0 = *(const bf16x8*)(a0p + off0);
            bf16x8 a1 = *(const bf16x8*)(a1p + off1);
            a0 = v0 ? a0 : z8;
            a1 = v1 ? a1 : z8;
            int t = (dy + 1) * 3 + (dx + 1);
#pragma unroll
            for (int n = 0; n < 4; ++n) {
                bf16x8 w = W1[(t * 4 + n) * 64 + lane];
                acc0[n] = __builtin_amdgcn_mfma_f32_16x16x32_bf16(a0, w, acc0[n], 0, 0, 0);
                acc1[n] = __builtin_amdgcn_mfma_f32_16x16x32_bf16(a1, w, acc1[n], 0, 0, 0);
            }
        }
    }
    // relu -> bf16 -> swizzled LDS rows 0..31
#pragma unroll
    for (int n = 0; n < 4; ++n)
#pragma unroll
        for (int r = 0; r < 4; ++r) {
            int row0 = g * 4 + r, ch = n * 16 + l15;
            int by0 = (row0 * 128 + ch * 2) ^ ((row0 & 7) << 4);
            int by1 = ((row0 + 16) * 128 + ch * 2) ^ ((row0 & 7) << 4);
            *(short*)(xb + by0) = f2bf(fmaxf(acc0[n][r], 0.f));
            *(short*)(xb + by1) = f2bf(fmaxf(acc1[n][r], 0.f));
        }

    // ---- GEMM2: 1x1, 64 -> 64 ----
#pragma unroll
    for (int n = 0; n < 4; ++n) {
        float b = b2[n * 16 + l15];
        acc0[n] = (f32x4){b, b, b, b};
        acc1[n] = (f32x4){b, b, b, b};
    }
#pragma unroll
    for (int c = 0; c < 2; ++c) {
        int by0 = (l15 * 128 + (32 * c + 8 * g) * 2) ^ ((l15 & 7) << 4);
        int by1 = ((l15 + 16) * 128 + (32 * c + 8 * g) * 2) ^ ((l15 & 7) << 4);
        bf16x8 a0 = *(const bf16x8*)(xb + by0);
        bf16x8 a1 = *(const bf16x8*)(xb + by1);
#pragma unroll
        for (int n = 0; n < 4; ++n) {
            bf16x8 w = W2[(c * 4 + n) * 64 + lane];
            acc0[n] = __builtin_amdgcn_mfma_f32_16x16x32_bf16(a0, w, acc0[n], 0, 0, 0);
            acc1[n] = __builtin_amdgcn_mfma_f32_16x16x32_bf16(a1, w, acc1[n], 0, 0, 0);
        }
    }
#pragma unroll
    for (int n = 0; n < 4; ++n)
#pragma unroll
        for (int r = 0; r < 4; ++r) {
            int row0 = g * 4 + r, ch = n * 16 + l15;
            int by0 = (row0 * 128 + ch * 2) ^ ((row0 & 7) << 4);
            int by1 = ((row0 + 16) * 128 + ch * 2) ^ ((row0 & 7) << 4);
            *(short*)(xb + by0) = f2bf(fmaxf(acc0[n][r], 0.f));
            *(short*)(xb + by1) = f2bf(fmaxf(acc1[n][r], 0.f));
        }

    // ---- GEMM3: 1x1, 64 -> 16 ----
    float b3v = b3[l15];
    f32x4 acc3a = {b3v, b3v, b3v, b3v};
    f32x4 acc3b = {b3v, b3v, b3v, b3v};
#pragma unroll
    for (int c = 0; c < 2; ++c) {
        int by0 = (l15 * 128 + (32 * c + 8 * g) * 2) ^ ((l15 & 7) << 4);
        int by1 = ((l15 + 16) * 128 + (32 * c + 8 * g) * 2) ^ ((l15 & 7) << 4);
        bf16x8 a0 = *(const bf16x8*)(xb + by0);
        bf16x8 a1 = *(const bf16x8*)(xb + by1);
        bf16x8 w = W3[c * 64 + lane];
        acc3a = __builtin_amdgcn_mfma_f32_16x16x32_bf16(a0, w, acc3a, 0, 0, 0);
        acc3b = __builtin_amdgcn_mfma_f32_16x16x32_bf16(a1, w, acc3b, 0, 0, 0);
    }

    // ---- 1x1, 16 -> 2 (f32) + flow add; 16-lane xor reduction over ch ----
    float w40 = w4[l15 * 2 + 0], w41 = w4[l15 * 2 + 1];
    float bb0 = b4[0], bb1 = b4[1];
#pragma unroll
    for (int tt = 0; tt < 2; ++tt) {
        f32x4 a3 = tt ? acc3b : acc3a;
#pragma unroll
        for (int r = 0; r < 4; ++r) {
            float v = fmaxf(a3[r], 0.f);
            float s0 = v * w40, s1 = v * w41;
#pragma unroll
            for (int m = 1; m < 16; m <<= 1) {
                s0 += __shfl_xor(s0, m);
                s1 += __shfl_xor(s1, m);
            }
            if (l15 == 0) {
                int pr = t0 + tt * 16 + g * 4 + r;
                float2 fl = *(const float2*)(flow + (size_t)pr * 2);
                float2 o; o.x = fl.x + bb0 + s0; o.y = fl.y + bb1 + s1;
                *(float2*)(fc + (size_t)pr * 2) = o;
            }
        }
    }
}

// ---------------------------------------------------------------------------
// POST mega-kernel bodies: warp_f32 (d_out) and 2x bilinear upsample.
// ---------------------------------------------------------------------------
__device__ __forceinline__ void warp_f32_body(
    int gid, const float* __restrict__ in1, const float* __restrict__ in2,
    const float* __restrict__ fcb, float* __restrict__ outf)
{
    int d   = (gid >= NPIX * 8);
    int g2  = gid - (d ? NPIX * 8 : 0);
    const float* img  = d ? in2 : in1;
    const float* flow = fcb + (size_t)d * NPIX * 2;
    float* out = outf + (size_t)d * NPIX * 32;

    int p   = g2 >> 3;
    int c4  = (g2 & 7) << 2;
    int b   = p >> 16;
    int i   = (p >> 8) & 255;
    int j   = p & 255;
    float2 f = *(const float2*)(flow + (size_t)p * 2);
    float qy = (float)i - f.x;
    float qx = (float)j - f.y;
    float fyf = fminf(fmaxf(floorf(qy), 0.0f), (float)(H_ - 2));
    float fxf = fminf(fmaxf(floorf(qx), 0.0f), (float)(W_ - 2));
    float ay = fminf(fmaxf(qy - fyf, 0.0f), 1.0f);
    float ax = fminf(fmaxf(qx - fxf, 0.0f), 1.0f);
    int fy = (int)fyf, fx = (int)fxf;
    const float* base = img + ((((size_t)b * H_ + fy) * W_ + fx) << 5) + c4;
    float4 tl = ld4(base);
    float4 tr = ld4(base + 32);
    float4 bl = ld4(base + W_ * 32);
    float4 br = ld4(base + W_ * 32 + 32);
    float4 r;
    { float t = tl.x + ax * (tr.x - tl.x); float u = bl.x + ax * (br.x - bl.x); r.x = t + ay * (u - t); }
    { float t = tl.y + ax * (tr.y - tl.y); float u = bl.y + ax * (br.y - bl.y); r.y = t + ay * (u - t); }
    { float t = tl.z + ax * (tr.z - tl.z); float u = bl.z + ax * (br.z - bl.z); r.z = t + ay * (u - t); }
    { float t = tl.w + ax * (tr.w - tl.w); float u = bl.w + ax * (br.w - bl.w); r.w = t + ay * (u - t); }
    *(float4*)(out + ((size_t)p << 5) + c4) = r;
}

__device__ __forceinline__ void upsample_body(
    int gid, const float* __restrict__ fcb, float* __restrict__ outup)
{
    const int NUP = B_ * 512 * 512;
    int d  = (gid >= NUP);
    int g2 = gid - (d ? NUP : 0);
    const float* fc = fcb + (size_t)d * NPIX * 2;
    float* out = outup + (size_t)d * NUP * 2;

    int b  = g2 >> 18;
    int oy = (g2 >> 9) & 511;
    int ox = g2 & 511;
    float iy = 0.5f * (float)oy - 0.25f;
    float ix = 0.5f * (float)ox - 0.25f;
    float y0f = floorf(iy), x0f = floorf(ix);
    float wy = iy - y0f, wx = ix - x0f;
    int y0 = min(max((int)y0f, 0), H_ - 1);
    int y1 = min(max((int)y0f + 1, 0), H_ - 1);
    int x0 = min(max((int)x0f, 0), W_ - 1);
    int x1 = min(max((int)x0f + 1, 0), W_ - 1);
    float2 v00 = *(const float2*)(fc + (((size_t)b * H_ + y0) * W_ + x0) * 2);
    float2 v01 = *(const float2*)(fc + (((size_t)b * H_ + y0) * W_ + x1) * 2);
    float2 v10 = *(const float2*)(fc + (((size_t)b * H_ + y1) * W_ + x0) * 2);
    float2 v11 = *(const float2*)(fc + (((size_t)b * H_ + y1) * W_ + x1) * 2);
    float2 r;
    { float t = v00.x + wx * (v01.x - v00.x); float u = v10.x + wx * (v11.x - v10.x); r.x = t + wy * (u - t); }
    { float t = v00.y + wx * (v01.y - v00.y); float u = v10.y + wx * (v11.y - v10.y); r.y = t + wy * (u - t); }
    *(float2*)(out + (size_t)g2 * 2) = r;
}

__global__ __launch_bounds__(256) void post_kernel(
    const float* __restrict__ in1, const float* __restrict__ in2,
    const float* __restrict__ fcb, float* __restrict__ outf,
    float* __restrict__ outup)
{
    const int NWF = 2 * NPIX * 8 / 256;   // 32768 warp_f32 blocks
    int blk = blockIdx.x;
    if (blk < NWF) {
        warp_f32_body(blk * 256 + threadIdx.x, in1, in2, fcb, outf);
    } else {
        upsample_body((blk - NWF) * 256 + threadIdx.x, fcb, outup);
    }
}

// ---------------------------------------------------------------------------
// d_in order = setup_inputs() dict order (interleaved per layer):
//   w_i = d_in[4+4i+2d], b_i = d_in[5+4i+2d]
// ---------------------------------------------------------------------------
extern "C" void kernel_launch(void* const* d_in, const int* in_sizes, int n_in,
                              void* d_out, int out_size, void* d_ws, size_t ws_size,
                              hipStream_t stream)
{
    (void)in_sizes; (void)n_in; (void)out_size; (void)ws_size;
    const float* input1 = (const float*)d_in[0];
    const float* input2 = (const float*)d_in[1];
    const float* fl12 = (const float*)d_in[2];
    const float* fl21 = (const float*)d_in[3];
    char* wsb = (char*)d_ws;
    short* xb1  = (short*)(wsb);                       // 32MB
    short* xb2  = (short*)(wsb + 33554432);            // 32MB
    short* wbf  = (short*)(wsb + 67108864);            // 2 x 32MB
    short* h0   = (short*)(wsb + 134217728);           // 2 x 32MB
    float* fcb  = (float*)(wsb + 201326592);           // 2 x 4MB
    short* wt0  = (short*)(wsb + 209715200);           // 5248*16 B
    short* wt1  = (short*)(wsb + 209715200 + 5248 * 16);
    float* outf = (float*)d_out;
    float* outup = outf + (size_t)2 * NPIX * 32;

    const int NPRE = 2 * NPIX * 8 / 256 + NPIX * 64 / 8 / 256 + (2 * 5248 + 255) / 256;
    pre_kernel<<<NPRE, 256, 0, stream>>>(
        input1, input2, fl12, fl21, xb1, xb2, wbf,
        (const float*)d_in[4],  (const float*)d_in[8],  (const float*)d_in[12], (const float*)d_in[16],
        (const float*)d_in[6],  (const float*)d_in[10], (const float*)d_in[14], (const float*)d_in[18],
        wt0, wt1);
    conv0_mfma_kernel<<<2 * NPIX / 256, 512, 0, stream>>>(
        xb1, xb2, wbf, wt0, wt1,
        (const float*)d_in[5], (const float*)d_in[7], h0);
    conv1_mfma_kernel<<<2 * NPIX / 256, 512, 0, stream>>>(
        h0, wt0, wt1,
        (const float*)d_in[9],  (const float*)d_in[11],
        (const float*)d_in[13], (const float*)d_in[15],
        (const float*)d_in[17], (const float*)d_in[19],
        (const float*)d_in[20], (const float*)d_in[22],
        (const float*)d_in[21], (const float*)d_in[23],
        fl12, fl21, fcb);
    const int NPOST = 2 * NPIX * 8 / 256 + 2 * B_ * 512 * 512 / 256;
    post_kernel<<<NPOST, 256, 0, stream>>>(input1, input2, fcb, outf, outup);
}